// Round 1
// baseline (626.566 us; speedup 1.0000x reference)
//
#include <hip/hip_runtime.h>

namespace {

constexpr int B_ = 2, C_ = 64, H_ = 192, W_ = 192;
constexpr int C4 = 256;
constexpr int NPIX = H_ * W_;                       // 36864
constexpr size_t NT = (size_t)B_ * C4 * NPIX;       // 18,874,368 elements per tensor
constexpr float EPSV = 1e-20f;

constexpr int TILE = 32;
constexpr int TLH = TILE + 2;   // 34: stage-1 halo grid
constexpr int TDH = TILE + 4;   // 36: d/cd halo grid

// ---------------- sums of the two weight tensors ----------------
__global__ __launch_bounds__(256) void k_sums(const float* __restrict__ sw,
                                              const float* __restrict__ cw,
                                              float* __restrict__ sums) {
    __shared__ float red[256];
    int tid = threadIdx.x;
    float a = 0.f;
    for (int i = tid; i < C4 * 9; i += 256) a += sw[i];
    red[tid] = a; __syncthreads();
    for (int s2 = 128; s2 > 0; s2 >>= 1) { if (tid < s2) red[tid] += red[tid + s2]; __syncthreads(); }
    if (tid == 0) sums[0] = red[0];
    __syncthreads();
    float b = 0.f;
    for (int i = tid; i < C4 * C4; i += 256) b += cw[i];
    red[tid] = b; __syncthreads();
    for (int s2 = 128; s2 > 0; s2 >>= 1) { if (tid < s2) red[tid] += red[tid + s2]; __syncthreads(); }
    if (tid == 0) sums[1] = red[0];
}

// ---------------- fused stage 1 + stage 2 (depthwise conv) ----------------
// One block per (b, c, 32x32 spatial tile). Produces X = cs_spatial*s_spatial
// and Y = cs_spatial for all 4 sub-channels of c.
__global__ __launch_bounds__(256) void k_stage12(
    const float* __restrict__ d, const float* __restrict__ cd,
    const float* __restrict__ s, const float* __restrict__ cs,
    const float* __restrict__ w_s_from_d, const float* __restrict__ w_prop,
    const float* __restrict__ sw, const float* __restrict__ sums,
    float* __restrict__ X, float* __restrict__ Y)
{
    __shared__ float ds_[TDH][TDH];
    __shared__ float cds_[TDH][TDH];
    __shared__ float sp_[4][TLH][TLH];   // cs_prop * s_prop (conv nom input)
    __shared__ float cp_[4][TLH][TLH];   // cs_prop        (conv den input)
    __shared__ float swl[4][9];

    int tid = threadIdx.x;
    int blk = blockIdx.x;
    constexpr int TX = W_ / TILE, TY = H_ / TILE;   // 6 x 6
    int tx0 = blk % TX; blk /= TX;
    int ty0 = blk % TY; blk /= TY;
    int c = blk % C_;
    int b = blk / C_;
    int h0 = ty0 * TILE, w0 = tx0 * TILE;

    const float* dbc  = d  + (size_t)(b * C_ + c) * NPIX;
    const float* cdbc = cd + (size_t)(b * C_ + c) * NPIX;

    // load d / cd with halo 2 (zero padding outside image)
    for (int i = tid; i < TDH * TDH; i += 256) {
        int y = i / TDH, x = i % TDH;
        int gh = h0 - 2 + y, gw = w0 - 2 + x;
        bool ok = (gh >= 0 && gh < H_ && gw >= 0 && gw < W_);
        ds_[y][x]  = ok ? dbc[gh * W_ + gw]  : 0.f;
        cds_[y][x] = ok ? cdbc[gh * W_ + gw] : 0.f;
    }
    if (tid < 36) swl[tid / 9][tid % 9] = sw[(c * 4 + tid / 9) * 9 + tid % 9];
    __syncthreads();

    float w0s = w_s_from_d[0];
    float wp  = w_prop[c];
    float inv_wp1 = 1.f / (wp + 1.f);
    float inv_sw  = 1.f / (sums[0] + EPSV);

    // stage 1 on the halo-1 grid (34x34). Only direction k=0 survives the
    // argmax/take_along_axis in the reference (identical stacked copies).
    for (int i = tid; i < TLH * TLH; i += 256) {
        int y = i / TLH, x = i % TLH;
        int gh = h0 - 1 + y, gw = w0 - 1 + x;
        if (gh >= 0 && gh < H_ && gw >= 0 && gw < W_) {
            int yy = y + 1, xx = x + 1;   // ds_ coords of (gh,gw)
            float mn  = ds_[yy - 1][xx - 1];
            float mx  = ds_[yy + 1][xx + 1];
            float cmn = cds_[yy - 1][xx - 1];
            float cmx = cds_[yy + 1][xx + 1];
            float r = mn / (mx + EPSV);
            r = fminf(fmaxf(r, 0.f), 1.f);
            float sfd = (1.f - w0s) * r + w0s * r * r;   // s_from_d
            float cfd = cmn * cmx;                        // cs_from_d
            size_t base = (size_t)((b * C_ + c) * 4) * NPIX + (size_t)gh * W_ + gw;
            #pragma unroll
            for (int k = 0; k < 4; ++k) {
                float s_v  = s[base + (size_t)k * NPIX];
                float cs_v = cs[base + (size_t)k * NPIX];
                float num = wp * cs_v * s_v + cfd * sfd;
                float den = wp * cs_v + cfd;
                float spv = num / (den + EPSV);   // s_prop
                float cpv = den * inv_wp1;        // cs_prop
                sp_[k][y][x] = cpv * spv;
                cp_[k][y][x] = cpv;
            }
        } else {
            #pragma unroll
            for (int k = 0; k < 4; ++k) { sp_[k][y][x] = 0.f; cp_[k][y][x] = 0.f; }
        }
    }
    __syncthreads();

    // stage 2: depthwise 3x3 cross-correlation, emit X and Y
    for (int i = tid; i < 4 * TILE * TILE; i += 256) {
        int k  = i >> 10;
        int rm = i & 1023;
        int ty = rm >> 5, tx = rm & 31;
        float nom = 0.f, den = 0.f;
        #pragma unroll
        for (int dy = 0; dy < 3; ++dy)
            #pragma unroll
            for (int dx = 0; dx < 3; ++dx) {
                float wgt = swl[k][dy * 3 + dx];
                nom = fmaf(wgt, sp_[k][ty + dy][tx + dx], nom);
                den = fmaf(wgt, cp_[k][ty + dy][tx + dx], den);
            }
        float csSp = den * inv_sw;            // cs_spatial
        float sSp  = nom / (den + EPSV);      // s_spatial
        size_t oidx = (size_t)(b * C4 + c * 4 + k) * NPIX + (size_t)(h0 + ty) * W_ + (w0 + tx);
        X[oidx] = csSp * sSp;
        Y[oidx] = csSp;
    }
}

// ---------------- stage 3: 256x256 channel mix (VALU GEMM) ----------------
// Block: 256 threads, 16 pixels, all 256 output channels.
// Thread owns 4 outputs x 4 pixels for nom2 and den2.
constexpr int TP = 16;
__global__ __launch_bounds__(256) void k_stage3(
    const float* __restrict__ X, const float* __restrict__ Y,
    const float* __restrict__ cwg, const float* __restrict__ sums,
    float* __restrict__ out)
{
    __shared__ float cwl[16][C4 + 1];   // [c_local][o], padded vs bank conflicts
    __shared__ float xl[16][TP];
    __shared__ float yl[16][TP];

    int tid = threadIdx.x;
    int pix0 = blockIdx.x * TP;
    int b = blockIdx.y;
    int obase = (tid & 63) * 4;
    int pbase = (tid >> 6) * 4;

    float accn[4][4] = {};
    float accd[4][4] = {};
    float inv_scw = 1.f / (sums[1] + EPSV);

    for (int c0 = 0; c0 < C4; c0 += 16) {
        __syncthreads();
        {
            int cl = tid & 15;
            int ob = tid >> 4;
            #pragma unroll
            for (int r = 0; r < 16; ++r) {
                int o = r * 16 + ob;
                cwl[cl][o] = cwg[o * C4 + c0 + cl];
            }
        }
        {
            int cl = tid / TP, p = tid % TP;
            size_t gi = (size_t)(b * C4 + c0 + cl) * NPIX + pix0 + p;
            xl[cl][p] = X[gi];
            yl[cl][p] = Y[gi];
        }
        __syncthreads();
        #pragma unroll
        for (int cl = 0; cl < 16; ++cl) {
            float w4[4], xv[4], yv[4];
            #pragma unroll
            for (int oi = 0; oi < 4; ++oi) w4[oi] = cwl[cl][obase + oi];
            #pragma unroll
            for (int pi = 0; pi < 4; ++pi) { xv[pi] = xl[cl][pbase + pi]; yv[pi] = yl[cl][pbase + pi]; }
            #pragma unroll
            for (int oi = 0; oi < 4; ++oi)
                #pragma unroll
                for (int pi = 0; pi < 4; ++pi) {
                    accn[oi][pi] = fmaf(w4[oi], xv[pi], accn[oi][pi]);
                    accd[oi][pi] = fmaf(w4[oi], yv[pi], accd[oi][pi]);
                }
        }
    }

    #pragma unroll
    for (int oi = 0; oi < 4; ++oi) {
        int o = obase + oi;
        #pragma unroll
        for (int pi = 0; pi < 4; ++pi) {
            size_t oidx = (size_t)(b * C4 + o) * NPIX + pix0 + pbase + pi;
            out[oidx]      = accn[oi][pi] / (accd[oi][pi] + EPSV);   // s_out
            out[NT + oidx] = accd[oi][pi] * inv_scw;                 // cs_out
        }
    }
}

} // namespace

extern "C" void kernel_launch(void* const* d_in, const int* in_sizes, int n_in,
                              void* d_out, int out_size, void* d_ws, size_t ws_size,
                              hipStream_t stream) {
    const float* d    = (const float*)d_in[0];
    const float* cd   = (const float*)d_in[1];
    const float* s    = (const float*)d_in[2];
    const float* cs   = (const float*)d_in[3];
    const float* w_s  = (const float*)d_in[4];
    const float* wprp = (const float*)d_in[5];
    const float* cw   = (const float*)d_in[6];
    const float* sw   = (const float*)d_in[7];
    float* out = (float*)d_out;

    float* X    = (float*)d_ws;
    float* Y    = X + NT;
    float* sums = Y + NT;

    k_sums<<<1, 256, 0, stream>>>(sw, cw, sums);
    k_stage12<<<dim3(B_ * C_ * (H_ / TILE) * (W_ / TILE)), 256, 0, stream>>>(
        d, cd, s, cs, w_s, wprp, sw, sums, X, Y);
    k_stage3<<<dim3(NPIX / TP, B_), 256, 0, stream>>>(X, Y, cw, sums, out);
}

// Round 2
// 411.910 us; speedup vs baseline: 1.5211x; 1.5211x over previous
//
#include <hip/hip_runtime.h>

namespace {

typedef unsigned short ushort_t;
typedef short bf16x8 __attribute__((ext_vector_type(8)));
typedef float f32x4 __attribute__((ext_vector_type(4)));

constexpr int B_ = 2, C_ = 64, H_ = 192, W_ = 192;
constexpr int C4 = 256;
constexpr int NPIX = H_ * W_;                       // 36864
constexpr size_t NT = (size_t)B_ * C4 * NPIX;       // 18,874,368
constexpr int PB = NPIX / 32;                       // 1152 pixel-blocks per batch
constexpr float EPSV = 1e-20f;

constexpr int TILE = 32;
constexpr int TLH = TILE + 2;   // 34
constexpr int TDH = TILE + 4;   // 36

__device__ __forceinline__ ushort_t f2bu(float x) {
    union { float f; unsigned u; } v; v.f = x;
    unsigned r = v.u + 0x7fffu + ((v.u >> 16) & 1u);   // RNE to bf16
    return (ushort_t)(r >> 16);
}
__device__ __forceinline__ float bu2f(ushort_t h) {
    union { unsigned u; float f; } v; v.u = ((unsigned)h) << 16;
    return v.f;
}

// ---------------- sums of the two weight tensors ----------------
__global__ __launch_bounds__(256) void k_sums(const float* __restrict__ sw,
                                              const float* __restrict__ cw,
                                              float* __restrict__ sums) {
    __shared__ float red[256];
    int tid = threadIdx.x;
    float a = 0.f;
    for (int i = tid; i < C4 * 9; i += 256) a += sw[i];
    red[tid] = a; __syncthreads();
    for (int s2 = 128; s2 > 0; s2 >>= 1) { if (tid < s2) red[tid] += red[tid + s2]; __syncthreads(); }
    if (tid == 0) sums[0] = red[0];
    __syncthreads();
    float b = 0.f;
    for (int i = tid; i < C4 * C4; i += 256) b += cw[i];
    red[tid] = b; __syncthreads();
    for (int s2 = 128; s2 > 0; s2 >>= 1) { if (tid < s2) red[tid] += red[tid + s2]; __syncthreads(); }
    if (tid == 0) sums[1] = red[0];
}

// ---------------- cw -> split bf16 hi/lo, [O=256][K=256] ----------------
__global__ __launch_bounds__(256) void k_prep(const float* __restrict__ cw,
                                              ushort_t* __restrict__ cwH,
                                              ushort_t* __restrict__ cwL) {
    int i = blockIdx.x * 256 + threadIdx.x;   // grid 256 -> 65536
    float w = cw[i];
    ushort_t h = f2bu(w);
    cwH[i] = h;
    cwL[i] = f2bu(w - bu2f(h));
}

// ---------------- fused stage 1 + stage 2 (depthwise conv) ----------------
// Emits XH/XL/YH/YL (split bf16 of cs_spatial*s_spatial and cs_spatial)
// in GEMM-blocked layout: element (b, pixblk, g=c4>>2, pix32, k=c4&3) at
// ((b*PB+pb)*64 + g)*128 + pix*4 + k.
__global__ __launch_bounds__(256) void k_stage12(
    const float* __restrict__ d, const float* __restrict__ cd,
    const float* __restrict__ s, const float* __restrict__ cs,
    const float* __restrict__ w_s_from_d, const float* __restrict__ w_prop,
    const float* __restrict__ sw, const float* __restrict__ sums,
    ushort_t* __restrict__ XH, ushort_t* __restrict__ XL,
    ushort_t* __restrict__ YH, ushort_t* __restrict__ YL)
{
    __shared__ float ds_[TDH][TDH];
    __shared__ float cds_[TDH][TDH];
    __shared__ float sp_[4][TLH][TLH];   // cs_prop * s_prop
    __shared__ float cp_[4][TLH][TLH];   // cs_prop
    __shared__ float swl[4][9];

    int tid = threadIdx.x;
    int blk = blockIdx.x;
    constexpr int TX = W_ / TILE, TY = H_ / TILE;   // 6 x 6
    int tx0 = blk % TX; blk /= TX;
    int ty0 = blk % TY; blk /= TY;
    int c = blk % C_;
    int b = blk / C_;
    int h0 = ty0 * TILE, w0 = tx0 * TILE;

    const float* dbc  = d  + (size_t)(b * C_ + c) * NPIX;
    const float* cdbc = cd + (size_t)(b * C_ + c) * NPIX;

    for (int i = tid; i < TDH * TDH; i += 256) {
        int y = i / TDH, x = i % TDH;
        int gh = h0 - 2 + y, gw = w0 - 2 + x;
        bool ok = (gh >= 0 && gh < H_ && gw >= 0 && gw < W_);
        ds_[y][x]  = ok ? dbc[gh * W_ + gw]  : 0.f;
        cds_[y][x] = ok ? cdbc[gh * W_ + gw] : 0.f;
    }
    if (tid < 36) swl[tid / 9][tid % 9] = sw[(c * 4 + tid / 9) * 9 + tid % 9];
    __syncthreads();

    float w0s = w_s_from_d[0];
    float wp  = w_prop[c];
    float inv_wp1 = 1.f / (wp + 1.f);
    float inv_sw  = 1.f / (sums[0] + EPSV);

    // stage 1 on halo-1 grid (only direction k=0 survives argmax in ref)
    for (int i = tid; i < TLH * TLH; i += 256) {
        int y = i / TLH, x = i % TLH;
        int gh = h0 - 1 + y, gw = w0 - 1 + x;
        if (gh >= 0 && gh < H_ && gw >= 0 && gw < W_) {
            int yy = y + 1, xx = x + 1;
            float mn  = ds_[yy - 1][xx - 1];
            float mx  = ds_[yy + 1][xx + 1];
            float cmn = cds_[yy - 1][xx - 1];
            float cmx = cds_[yy + 1][xx + 1];
            float r = mn / (mx + EPSV);
            r = fminf(fmaxf(r, 0.f), 1.f);
            float sfd = (1.f - w0s) * r + w0s * r * r;
            float cfd = cmn * cmx;
            size_t base = (size_t)((b * C_ + c) * 4) * NPIX + (size_t)gh * W_ + gw;
            #pragma unroll
            for (int k = 0; k < 4; ++k) {
                float s_v  = s[base + (size_t)k * NPIX];
                float cs_v = cs[base + (size_t)k * NPIX];
                float num = wp * cs_v * s_v + cfd * sfd;
                float den = wp * cs_v + cfd;
                float spv = num / (den + EPSV);
                float cpv = den * inv_wp1;
                sp_[k][y][x] = cpv * spv;
                cp_[k][y][x] = cpv;
            }
        } else {
            #pragma unroll
            for (int k = 0; k < 4; ++k) { sp_[k][y][x] = 0.f; cp_[k][y][x] = 0.f; }
        }
    }
    __syncthreads();

    // stage 2: depthwise 3x3, pack 4 sub-channels per pixel, write blocked bf16
    int pbw = w0 >> 5;
    for (int i = tid; i < TILE * TILE; i += 256) {
        int ty = i >> 5, tx = i & 31;
        ushort_t xh[4], xl[4], yh[4], yl[4];
        #pragma unroll
        for (int k = 0; k < 4; ++k) {
            float nom = 0.f, den = 0.f;
            #pragma unroll
            for (int dy = 0; dy < 3; ++dy)
                #pragma unroll
                for (int dx = 0; dx < 3; ++dx) {
                    float wgt = swl[k][dy * 3 + dx];
                    nom = fmaf(wgt, sp_[k][ty + dy][tx + dx], nom);
                    den = fmaf(wgt, cp_[k][ty + dy][tx + dx], den);
                }
            float csSp = den * inv_sw;
            float sSp  = nom / (den + EPSV);
            float xv = csSp * sSp;
            float yv = csSp;
            xh[k] = f2bu(xv); xl[k] = f2bu(xv - bu2f(xh[k]));
            yh[k] = f2bu(yv); yl[k] = f2bu(yv - bu2f(yh[k]));
        }
        int pb = (h0 + ty) * (W_ / 32) + pbw;
        size_t base = ((size_t)(b * PB + pb) * 64 + c) * 128 + tx * 4;
        ushort4 v;
        v.x = xh[0]; v.y = xh[1]; v.z = xh[2]; v.w = xh[3]; *(ushort4*)(XH + base) = v;
        v.x = xl[0]; v.y = xl[1]; v.z = xl[2]; v.w = xl[3]; *(ushort4*)(XL + base) = v;
        v.x = yh[0]; v.y = yh[1]; v.z = yh[2]; v.w = yh[3]; *(ushort4*)(YH + base) = v;
        v.x = yl[0]; v.y = yl[1]; v.z = yl[2]; v.w = yl[3]; *(ushort4*)(YL + base) = v;
    }
}

// ---------------- stage 3: split-bf16 MFMA GEMM ----------------
// Block: 512 threads (8 waves), 32 pixels x all 256 outputs.
// Wave w: o in [w*32, w*32+32) (2 m-frags), 32 pixels (2 n-frags).
// D = cw * Xdata: A[m=o][k=c], B[k=c][n=pix].
__device__ __forceinline__ bf16x8 ldA(const ushort_t* p) {
    return *(const bf16x8*)p;   // 16B contiguous
}
__device__ __forceinline__ bf16x8 ldB(const ushort_t* p) {
    union { bf16x8 v; ushort4 u[2]; } t;
    t.u[0] = *(const ushort4*)p;
    t.u[1] = *(const ushort4*)(p + 128);
    return t.v;
}

__global__ __launch_bounds__(512) void k_stage3(
    const ushort_t* __restrict__ XH, const ushort_t* __restrict__ XL,
    const ushort_t* __restrict__ YH, const ushort_t* __restrict__ YL,
    const ushort_t* __restrict__ cwH, const ushort_t* __restrict__ cwL,
    const float* __restrict__ sums, float* __restrict__ out)
{
    int tid  = threadIdx.x;
    int wave = tid >> 6, lane = tid & 63;
    int l15 = lane & 15, l4 = lane >> 4;
    int pb = blockIdx.x;
    int b  = blockIdx.y;
    int o0 = wave * 32;

    const ushort_t* ah0 = cwH + (size_t)(o0 + l15) * C4;
    const ushort_t* ah1 = cwH + (size_t)(o0 + 16 + l15) * C4;
    const ushort_t* al0 = cwL + (size_t)(o0 + l15) * C4;
    const ushort_t* al1 = cwL + (size_t)(o0 + 16 + l15) * C4;

    size_t xbase = (size_t)(b * PB + pb) * 8192;   // 64 groups * 128 elements

    f32x4 accn[2][2] = {};
    f32x4 accd[2][2] = {};

    #pragma unroll
    for (int ks = 0; ks < 8; ++ks) {
        int ka = ks * 32 + l4 * 8;
        bf16x8 a0h = ldA(ah0 + ka);
        bf16x8 a1h = ldA(ah1 + ka);
        bf16x8 a0l = ldA(al0 + ka);
        bf16x8 a1l = ldA(al1 + ka);

        size_t be0 = xbase + (size_t)(ks * 8 + l4 * 2) * 128 + l15 * 4;
        size_t be1 = be0 + 16 * 4;
        bf16x8 bxh[2], bxl[2], byh[2], byl[2];
        bxh[0] = ldB(XH + be0); bxh[1] = ldB(XH + be1);
        bxl[0] = ldB(XL + be0); bxl[1] = ldB(XL + be1);
        byh[0] = ldB(YH + be0); byh[1] = ldB(YH + be1);
        byl[0] = ldB(YL + be0); byl[1] = ldB(YL + be1);

        #pragma unroll
        for (int n = 0; n < 2; ++n) {
            accn[0][n] = __builtin_amdgcn_mfma_f32_16x16x32_bf16(a0h, bxh[n], accn[0][n], 0, 0, 0);
            accn[0][n] = __builtin_amdgcn_mfma_f32_16x16x32_bf16(a0h, bxl[n], accn[0][n], 0, 0, 0);
            accn[0][n] = __builtin_amdgcn_mfma_f32_16x16x32_bf16(a0l, bxh[n], accn[0][n], 0, 0, 0);
            accn[1][n] = __builtin_amdgcn_mfma_f32_16x16x32_bf16(a1h, bxh[n], accn[1][n], 0, 0, 0);
            accn[1][n] = __builtin_amdgcn_mfma_f32_16x16x32_bf16(a1h, bxl[n], accn[1][n], 0, 0, 0);
            accn[1][n] = __builtin_amdgcn_mfma_f32_16x16x32_bf16(a1l, bxh[n], accn[1][n], 0, 0, 0);
            accd[0][n] = __builtin_amdgcn_mfma_f32_16x16x32_bf16(a0h, byh[n], accd[0][n], 0, 0, 0);
            accd[0][n] = __builtin_amdgcn_mfma_f32_16x16x32_bf16(a0h, byl[n], accd[0][n], 0, 0, 0);
            accd[0][n] = __builtin_amdgcn_mfma_f32_16x16x32_bf16(a0l, byh[n], accd[0][n], 0, 0, 0);
            accd[1][n] = __builtin_amdgcn_mfma_f32_16x16x32_bf16(a1h, byh[n], accd[1][n], 0, 0, 0);
            accd[1][n] = __builtin_amdgcn_mfma_f32_16x16x32_bf16(a1h, byl[n], accd[1][n], 0, 0, 0);
            accd[1][n] = __builtin_amdgcn_mfma_f32_16x16x32_bf16(a1l, byh[n], accd[1][n], 0, 0, 0);
        }
    }

    float inv_scw = 1.f / (sums[1] + EPSV);
    #pragma unroll
    for (int m = 0; m < 2; ++m)
        #pragma unroll
        for (int n = 0; n < 2; ++n)
            #pragma unroll
            for (int r = 0; r < 4; ++r) {
                int o   = o0 + m * 16 + l4 * 4 + r;
                int pix = pb * 32 + n * 16 + l15;
                size_t oidx = ((size_t)(b * C4 + o)) * NPIX + pix;
                float nv = accn[m][n][r], dv = accd[m][n][r];
                out[oidx]      = nv / (dv + EPSV);
                out[NT + oidx] = dv * inv_scw;
            }
}

} // namespace

extern "C" void kernel_launch(void* const* d_in, const int* in_sizes, int n_in,
                              void* d_out, int out_size, void* d_ws, size_t ws_size,
                              hipStream_t stream) {
    const float* d    = (const float*)d_in[0];
    const float* cd   = (const float*)d_in[1];
    const float* s    = (const float*)d_in[2];
    const float* cs   = (const float*)d_in[3];
    const float* w_s  = (const float*)d_in[4];
    const float* wprp = (const float*)d_in[5];
    const float* cw   = (const float*)d_in[6];
    const float* sw   = (const float*)d_in[7];
    float* out = (float*)d_out;

    ushort_t* XH  = (ushort_t*)d_ws;
    ushort_t* XL  = XH + NT;
    ushort_t* YH  = XL + NT;
    ushort_t* YL  = YH + NT;
    ushort_t* cwH = YL + NT;
    ushort_t* cwL = cwH + C4 * C4;
    float* sums   = (float*)(cwL + C4 * C4);

    k_sums<<<1, 256, 0, stream>>>(sw, cw, sums);
    k_prep<<<C4, 256, 0, stream>>>(cw, cwH, cwL);
    k_stage12<<<dim3(B_ * C_ * (H_ / TILE) * (W_ / TILE)), 256, 0, stream>>>(
        d, cd, s, cs, w_s, wprp, sw, sums, XH, XL, YH, YL);
    k_stage3<<<dim3(PB, B_), 512, 0, stream>>>(XH, XL, YH, YL, cwH, cwL, sums, out);
}